// Round 12
// baseline (2312.882 us; speedup 1.0000x reference)
//
#include <hip/hip_runtime.h>
#include <math.h>

typedef __bf16 bf16_t;
typedef bf16_t bf16x8 __attribute__((ext_vector_type(8)));
typedef bf16_t bf16x4 __attribute__((ext_vector_type(4)));
typedef float  f32x4  __attribute__((ext_vector_type(4)));
typedef unsigned long long u64_t;

#define NB 32
#define NN 512
#define NH 64
#define NF 384
#define TSTEPS 48

static __device__ __forceinline__ f32x4 mfma16(bf16x8 a, bf16x8 b, f32x4 c){
  return __builtin_amdgcn_mfma_f32_16x16x32_bf16(a, b, c, 0, 0, 0);
}
static __device__ __forceinline__ void gload16(char* lds, const char* g){
  __builtin_amdgcn_global_load_lds((const __attribute__((address_space(1))) void*)g,
                                   (__attribute__((address_space(3))) void*)lds, 16, 0, 0);
}
static __device__ __forceinline__ unsigned pack2(float a, float b){
  bf16_t x = (bf16_t)a, y = (bf16_t)b;
  unsigned short ux = __builtin_bit_cast(unsigned short, x);
  unsigned short uy = __builtin_bit_cast(unsigned short, y);
  return (unsigned)ux | ((unsigned)uy << 16);
}

// ---------------- setup kernels ---------------------------------------------------
__global__ __launch_bounds__(256) void k_s2f(const float* __restrict__ S,
                                             float* __restrict__ S2f){
  int idx = blockIdx.x * 256 + threadIdx.x;
  int n = idx >> 9, m = idx & 511;
  float acc = 0.f;
  #pragma unroll 8
  for (int k = 0; k < 512; ++k) acc += S[n * 512 + k] * S[k * 512 + m];
  S2f[idx] = acc;
}

__global__ __launch_bounds__(256) void k_prepS(const float* __restrict__ S,
                                               const float* __restrict__ S2f,
                                               char* __restrict__ dst){
  int id = blockIdx.x * 256 + threadIdx.x;       // 524288
  int r = id >> 9, k = id & 511;
  float v = (r < 512) ? S[r * 512 + k] : S2f[(r - 512) * 512 + k];
  int rt = r >> 5, rr = r & 31, kt = k >> 6, kk = k & 63;
  size_t off = ((size_t)(rt * 8 + kt)) * 4096 + (size_t)(((rr * 128 + 2 * kk)) ^ ((rr & 7) << 4));
  *(bf16_t*)(dst + off) = (bf16_t)v;
}

__global__ __launch_bounds__(256) void k_prepW(const float* __restrict__ W,
                                               char* __restrict__ dst, int OD){
  int i = blockIdx.x * 256 + threadIdx.x;
  int total = 2 * NF * OD;
  if (i >= total) return;
  int l = i / (NF * OD), rem = i - l * (NF * OD);
  int o = rem / NF, f = rem - o * NF;
  const float* Wl = W + (size_t)l * NF * OD;
  float v;
  if (f < 128)      v = Wl[f * OD + o] - Wl[(256 + f) * OD + o];
  else if (f < 256) v = Wl[f * OD + o];
  else              v = 2.f * Wl[f * OD + o];
  int kt = f >> 6, kk = f & 63;
  size_t off = (size_t)l * (6 * OD * 128) + (size_t)kt * (OD * 128)
             + (size_t)(((o * 128 + 2 * kk)) ^ ((o & 7) << 4));
  *(bf16_t*)(dst + off) = (bf16_t)v;
}

__global__ __launch_bounds__(256) void k_hinit(const float* __restrict__ h0,
                                               float* __restrict__ hNf,
                                               bf16_t* __restrict__ hN){
  size_t i = ((size_t)blockIdx.x * 256 + threadIdx.x) * 8;
  f32x4 a = *(const f32x4*)&h0[i], b = *(const f32x4*)&h0[i + 4];
  *(f32x4*)&hNf[i] = a; *(f32x4*)&hNf[i + 4] = b;
  bf16x8 v;
  #pragma unroll
  for (int q = 0; q < 4; ++q){ v[q] = (bf16_t)a[q]; v[q + 4] = (bf16_t)b[q]; }
  *(bf16x8*)&hN[i] = v;
}

// ---------------- gate kernel (R11 body + rhT write; grid (256,2), t = p - l) -----
__global__ __launch_bounds__(512, 4) void k_gate(
    const float* __restrict__ inputs, const float* __restrict__ curp, int p,
    const bf16_t* __restrict__ hN, const char* __restrict__ SP,
    const char* __restrict__ WgP, const float* __restrict__ bga,
    bf16_t* __restrict__ rhN, bf16_t* __restrict__ rhT,
    float* __restrict__ uN, bf16_t* __restrict__ Dx)
{
  const int l = blockIdx.y;
  const int t = p - l;
  if (t < 0 || t >= TSTEPS) return;

  __shared__ char smem[81920];
  char* const A0 = smem;            char* const A1 = smem + 16384;
  char* const B0 = smem + 32768;    char* const B1 = smem + 49152;
  char* const FT = smem;            // feat 64x384 swz (49152)
  char* const W0 = smem + 49152;    // overlays B1 -> only load AFTER K-loop!
  char* const W1 = smem + 65536;
  char* const RL = smem + 49152;    // rh 64x64 bf16 (8K, after dense)
  char* const UL = smem + 57344;    // u  64x64 f32  (16K)

  const int L = blockIdx.x;                 // 256 = 8 bx x 32 b
  const int b  = (L & 7) + ((L >> 6) << 3);
  const int bx = (L >> 3) & 7;
  const int n0 = bx * 64;
  const int tid = threadIdx.x, lane = tid & 63, w = tid >> 6;
  const int fr = lane & 15, ko = (lane >> 4) * 8, ro = (lane >> 4) * 4;
  const int pp = tid >> 4, q4 = tid & 15;
  const int wr = w >> 2, wc = w & 3;        // diffusion tiling
  const int wn = w & 1, wo = w >> 1;        // dense tiling

  const float* xall = l ? curp : inputs;
  const float*  xs = xall + ((size_t)t * NB + b) * NN * NH;
  const bf16_t* hbg = hN + ((size_t)(l * NB + b)) * NN * NH;
  const char* const WgPl = WgP + (size_t)l * 98304;
  const float* const bg = bga + l * 128;
  bf16_t* const rh_l  = rhN + (size_t)l * NB * NN * NH;
  bf16_t* const rhT_l = rhT + (size_t)l * NB * NN * NH;
  float*  const u_l   = uN  + (size_t)l * NB * NN * NH;
  bf16_t* const Dx_l  = Dx  + (size_t)l * NB * NN * 128;

  f32x4 acc[4][2] = {};
  f32x4 rx0[2], rx1[2]; u64_t rh0[2], rh1[2];
  char* const Abuf[2] = { A0, A1 };
  char* const Bbuf[2] = { B0, B1 };

  auto ldB = [&](int kt, int s){
    int m = kt * 64 + 2 * pp;
    const float* xr = xs + (size_t)m * NH + q4 * 4;
    rx0[s] = *(const f32x4*)xr; rx1[s] = *(const f32x4*)(xr + NH);
    const bf16_t* hr = hbg + (size_t)m * NH + q4 * 4;
    rh0[s] = *(const u64_t*)hr; rh1[s] = *(const u64_t*)(hr + NH);
  };
  auto stB = [&](int s, char* Bb){
    int mby = 4 * pp;
    #pragma unroll
    for (int i = 0; i < 4; ++i){
      int c = q4 * 4 + i;
      *(unsigned*)(Bb + ((c * 128 + mby) ^ (((c >> 2) & 7) << 4))) = pack2(rx0[s][i], rx1[s][i]);
      int c2 = c + 64;
      unsigned uh = (unsigned)((rh0[s] >> (16 * i)) & 0xffffULL)
                  | ((unsigned)((rh1[s] >> (16 * i)) & 0xffffULL) << 16);
      *(unsigned*)(Bb + ((c2 * 128 + mby) ^ (((c2 >> 2) & 7) << 4))) = uh;
    }
  };
  auto gloadA = [&](int kt, char* Ab){
    #pragma unroll
    for (int i = 0; i < 2; ++i){
      int c = w * 2 + i;                  // 16 chunks of 1KB
      int ti = c >> 2;                    // 0..3
      int rt = (ti < 2) ? (bx * 2 + ti) : (16 + bx * 2 + (ti - 2));
      gload16(Ab + c * 1024,
              SP + ((size_t)(rt * 8 + kt)) * 4096 + (c & 3) * 1024 + lane * 16);
    }
  };
  auto gloadW = [&](int j, char* Wb){
    const char* src = WgPl + (size_t)j * 16384 + (w * 64 + lane) * 16;
    gload16(Wb + w * 1024, src);
    gload16(Wb + 8192 + w * 1024, src + 8192);
  };
  auto dmm = [&](const char* Ab, const char* Bb){
    #pragma unroll
    for (int kh = 0; kh < 2; ++kh){
      int kb = 2 * (kh * 32 + ko);
      bf16x8 af[4], bf_[2];
      #pragma unroll
      for (int fm = 0; fm < 4; ++fm){
        int r = wr * 64 + fm * 16 + fr;
        af[fm] = *(const bf16x8*)(Ab + (r >> 5) * 4096 + ((((r & 31) * 128 + kb)) ^ ((r & 7) << 4)));
      }
      #pragma unroll
      for (int fc = 0; fc < 2; ++fc){
        int c = wc * 32 + fc * 16 + fr;
        bf_[fc] = *(const bf16x8*)(Bb + ((c * 128 + kb) ^ (((c >> 2) & 7) << 4)));
      }
      #pragma unroll
      for (int fm = 0; fm < 4; ++fm)
        #pragma unroll
        for (int fc = 0; fc < 2; ++fc)
          acc[fm][fc] = mfma16(af[fm], bf_[fc], acc[fm][fc]);
    }
  };

  // prologue: DMA-first (NO W prefetch here: W0 aliases B1)
  gloadA(0, A0);
  ldB(0, 0); stB(0, B0);
  ldB(1, 1);
  __syncthreads();

  // K-loop: 1 barrier per iteration, DMA issued before VALU staging
  #pragma unroll
  for (int kt = 0; kt < 8; ++kt){
    if (kt < 7){
      gloadA(kt + 1, Abuf[(kt + 1) & 1]);
      stB((kt + 1) & 1, Bbuf[(kt + 1) & 1]);
    }
    dmm(Abuf[kt & 1], Bbuf[kt & 1]);
    __syncthreads();
    if (kt < 6) ldB(kt + 2, (kt + 2) & 1);
  }

  // W chunks 0,1 prefetch — B1 now dead; in flight during feat fill/scatter
  gloadW(0, W0); gloadW(1, W1);

  // ---- feat fill (x,h -> cols 0..127) + diffusion scatter (128..383) ----
  #pragma unroll
  for (int s = 0; s < 2; ++s){
    int i = tid + s * 512;
    int row = i >> 4, c8 = (i & 15) * 8;
    char* fdst = FT + (((row * 768 + 2 * c8)) ^ ((row & 7) << 4));
    if (c8 < 64){
      const float* xr = xs + (size_t)(n0 + row) * NH + c8;
      f32x4 a = *(const f32x4*)xr, bq = *(const f32x4*)(xr + 4);
      bf16x8 v;
      #pragma unroll
      for (int q = 0; q < 4; ++q){ v[q] = (bf16_t)a[q]; v[q + 4] = (bf16_t)bq[q]; }
      *(bf16x8*)fdst = v;
    } else {
      *(bf16x8*)fdst = *(const bf16x8*)(hbg + (size_t)(n0 + row) * NH + (c8 - 64));
    }
  }
  #pragma unroll
  for (int fm = 0; fm < 4; ++fm)
    #pragma unroll
    for (int fc = 0; fc < 2; ++fc)
      #pragma unroll
      for (int q = 0; q < 4; ++q){
        int dr = wr * 64 + fm * 16 + ro + q;       // 0..127
        int nn = dr & 63;
        int col = ((dr < 64) ? 128 : 256) + wc * 32 + fc * 16 + fr;
        *(bf16_t*)(FT + (((nn * 768 + 2 * col)) ^ ((nn & 7) << 4))) = (bf16_t)acc[fm][fc][q];
      }
  __syncthreads();

  // Dx dump (x-halves of diffusion for cand reuse)
  #pragma unroll
  for (int s = 0; s < 2; ++s){
    int i = tid + s * 512;
    int row = i >> 4, d8 = (i & 15) * 8;
    int col = (d8 < 64) ? 128 + d8 : 256 + (d8 - 64);
    bf16x8 v = *(const bf16x8*)(FT + (((row * 768 + 2 * col)) ^ ((row & 7) << 4)));
    *(bf16x8*)&Dx_l[((size_t)b * NN + n0 + row) * 128 + d8] = v;
  }

  // ---- dense K=384, W double-buffer (chunks 0,1 already in flight) ----
  f32x4 gd[2][2] = {};
  #pragma unroll
  for (int j = 0; j < 6; ++j){
    const char* Wb = (j & 1) ? W1 : W0;
    #pragma unroll
    for (int kh = 0; kh < 2; ++kh){
      int kbf = 2 * (j * 64 + kh * 32 + ko);
      int kbw = 2 * (kh * 32 + ko);
      bf16x8 af[2];
      #pragma unroll
      for (int fm = 0; fm < 2; ++fm){
        int r = wn * 32 + fm * 16 + fr;
        af[fm] = *(const bf16x8*)(FT + ((r * 768 + kbf) ^ ((r & 7) << 4)));
      }
      #pragma unroll
      for (int fo = 0; fo < 2; ++fo){
        int orow = wo * 32 + fo * 16 + fr;
        bf16x8 bw = *(const bf16x8*)(Wb + ((orow * 128 + kbw) ^ ((orow & 7) << 4)));
        #pragma unroll
        for (int fm = 0; fm < 2; ++fm)
          gd[fm][fo] = mfma16(af[fm], bw, gd[fm][fo]);
      }
    }
    __syncthreads();
    if (j < 4) gloadW(j + 2, (j & 1) ? W1 : W0);
  }

  // ---- epilogue: sigmoid -> rh / u tiles in LDS ----
  #pragma unroll
  for (int fm = 0; fm < 2; ++fm)
    #pragma unroll
    for (int fo = 0; fo < 2; ++fo){
      int o = wo * 32 + fo * 16 + fr;
      float bias = bg[o];
      #pragma unroll
      for (int q = 0; q < 4; ++q){
        int nn = wn * 32 + fm * 16 + ro + q;
        float g = 1.f / (1.f + __expf(-(gd[fm][fo][q] + bias)));
        if (o < 64){
          float hv = (float)*(const bf16_t*)(FT + (((nn * 768 + 2 * (64 + o))) ^ ((nn & 7) << 4)));
          *(bf16_t*)(RL + ((nn * 128 + 2 * o) ^ ((nn & 7) << 4))) = (bf16_t)(g * hv);
        } else {
          *(float*)(UL + ((nn * 256 + 4 * (o - 64)) ^ ((nn & 7) << 5))) = g;
        }
      }
    }
  __syncthreads();
  {
    int row = tid >> 3, o8 = (tid & 7) * 8;
    bf16x8 v = *(const bf16x8*)(RL + ((row * 128 + 2 * o8) ^ ((row & 7) << 4)));
    *(bf16x8*)&rh_l[((size_t)b * NN + n0 + row) * NH + o8] = v;
    int base = (row * 256 + 4 * o8) ^ ((row & 7) << 5);
    f32x4 u0 = *(const f32x4*)(UL + base);
    f32x4 u1 = *(const f32x4*)(UL + base + 16);
    size_t gi = ((size_t)b * NN + n0 + row) * NH + o8;
    *(f32x4*)&u_l[gi] = u0; *(f32x4*)&u_l[gi + 4] = u1;
    // rhT write: [o][n] transposed, coalesced 16B per thread
    int o = tid >> 3, n8 = (tid & 7) * 8;
    bf16x8 tv;
    #pragma unroll
    for (int q = 0; q < 8; ++q){
      int nn = n8 + q;
      tv[q] = *(const bf16_t*)(RL + ((nn * 128 + 2 * o) ^ ((nn & 7) << 4)));
    }
    *(bf16x8*)&rhT_l[((size_t)b * NH + o) * NN + n0 + n8] = tv;
  }
}

// ---------------- candidate kernel (direct-B from rhT, 3-phase dense) -------------
__global__ __launch_bounds__(512, 4) void k_cand(
    const float* __restrict__ inputs, int p,
    const bf16_t* __restrict__ rhN, const bf16_t* __restrict__ rhT,
    const bf16_t* __restrict__ Dx,
    const char* __restrict__ SP, const char* __restrict__ WcP,
    const float* __restrict__ bca, const float* __restrict__ uN,
    float* __restrict__ hNf, bf16_t* __restrict__ hN,
    float* __restrict__ outp)
{
  const int l = blockIdx.y;
  const int t = p - l;
  if (t < 0 || t >= TSTEPS) return;

  __shared__ char smem[81920];
  char* const A0 = smem;            char* const A1 = smem + 16384;
  char* const FT = smem;            // feat 64x384 swz (49152), overlays A
  char* const W0 = smem + 49152;    char* const W1 = smem + 65536;  // 16KB each
  char* const CL = smem + 49152;    // c 64x64 f32 (16K, after dense)

  const int L = blockIdx.x;
  const int b  = (L & 7) + ((L >> 6) << 3);
  const int bx = (L >> 3) & 7;
  const int n0 = bx * 64;
  const int tid = threadIdx.x, lane = tid & 63, w = tid >> 6;
  const int fr = lane & 15, ko = (lane >> 4) * 8, ro = (lane >> 4) * 4;
  const int wr = w >> 2, wc = w & 3;
  const int wn = w & 1, wo = w >> 1;

  float* const cur = outp + (size_t)2 * NB * NN * NH;
  const float* xall = l ? cur : inputs;
  const float*  xs = xall + ((size_t)t * NB + b) * NN * NH;
  const bf16_t* rbg  = rhN + ((size_t)(l * NB + b)) * NN * NH;
  const bf16_t* rTg  = rhT + ((size_t)(l * NB + b)) * NN * NH;   // [o][n]
  const char* const WcPl = WcP + (size_t)l * 49152;
  const float* const bc = bca + l * 64;
  const bf16_t* const Dx_l = Dx + (size_t)l * NB * NN * 128;
  const float* const u_l = uN + (size_t)l * NB * NN * NH;
  float*  const hNf_l = hNf + (size_t)l * NB * NN * NH;
  bf16_t* const hN_l  = hN  + (size_t)l * NB * NN * NH;
  float* const fin = outp + (size_t)l * NB * NN * NH;

  f32x4 ca[4] = {};
  char* const Abuf[2] = { A0, A1 };

  auto gloadA = [&](int kt, char* Ab){
    #pragma unroll
    for (int i = 0; i < 2; ++i){
      int c = w * 2 + i;
      int ti = c >> 2;
      int rt = (ti < 2) ? (bx * 2 + ti) : (16 + bx * 2 + (ti - 2));
      gload16(Ab + c * 1024,
              SP + ((size_t)(rt * 8 + kt)) * 4096 + (c & 3) * 1024 + lane * 16);
    }
  };
  // W chunk-pair j (128 k-cols = prep chunks 2j,2j+1) -> 16KB buffer
  auto gloadW2 = [&](int j, char* Wb){
    const char* src = WcPl + (size_t)(2 * j) * 8192 + (w * 64 + lane) * 16;
    gload16(Wb + w * 1024, src);
    gload16(Wb + 8192 + w * 1024, src + 8192);
  };
  // diffusion MFMA: B-frag direct from global rhT (8 consecutive m at fixed col c)
  auto cmm = [&](const char* Ab, int kt){
    #pragma unroll
    for (int kh = 0; kh < 2; ++kh){
      int kb = 2 * (kh * 32 + ko);
      int c = wc * 16 + fr;
      bf16x8 bf_ = *(const bf16x8*)&rTg[(size_t)c * NN + kt * 64 + kh * 32 + ko];
      #pragma unroll
      for (int fm = 0; fm < 4; ++fm){
        int r = wr * 64 + fm * 16 + fr;
        bf16x8 af = *(const bf16x8*)(Ab + (r >> 5) * 4096 + ((((r & 31) * 128 + kb)) ^ ((r & 7) << 4)));
        ca[fm] = mfma16(af, bf_, ca[fm]);
      }
    }
  };

  gloadA(0, A0);
  gloadW2(0, W0); gloadW2(1, W1);   // safe: W regions don't alias A here
  __syncthreads();

  #pragma unroll
  for (int kt = 0; kt < 8; ++kt){
    if (kt < 7) gloadA(kt + 1, Abuf[(kt + 1) & 1]);
    cmm(Abuf[kt & 1], kt);
    __syncthreads();
  }

  // ---- feat fill: x(0-63), rh(64-127), Dx(128-191/256-319) + scatter(192/320) ----
  #pragma unroll
  for (int s = 0; s < 2; ++s){
    int i = tid + s * 512;
    int row = i >> 4, c8 = (i & 15) * 8;
    char* fdst = FT + (((row * 768 + 2 * c8)) ^ ((row & 7) << 4));
    if (c8 < 64){
      const float* xr = xs + (size_t)(n0 + row) * NH + c8;
      f32x4 a = *(const f32x4*)xr, bq = *(const f32x4*)(xr + 4);
      bf16x8 v;
      #pragma unroll
      for (int q = 0; q < 4; ++q){ v[q] = (bf16_t)a[q]; v[q + 4] = (bf16_t)bq[q]; }
      *(bf16x8*)fdst = v;
    } else {
      *(bf16x8*)fdst = *(const bf16x8*)(rbg + (size_t)(n0 + row) * NH + (c8 - 64));
    }
    int col = (c8 < 64) ? 128 + c8 : 256 + (c8 - 64);
    bf16x8 dv = *(const bf16x8*)&Dx_l[((size_t)b * NN + n0 + row) * 128 + c8];
    *(bf16x8*)(FT + (((row * 768 + 2 * col)) ^ ((row & 7) << 4))) = dv;
  }
  #pragma unroll
  for (int fm = 0; fm < 4; ++fm)
    #pragma unroll
    for (int q = 0; q < 4; ++q){
      int dr = wr * 64 + fm * 16 + ro + q;
      int nn = dr & 63;
      int col = ((dr < 64) ? 192 : 320) + wc * 16 + fr;
      *(bf16_t*)(FT + (((nn * 768 + 2 * col)) ^ ((nn & 7) << 4))) = (bf16_t)ca[fm][q];
    }
  __syncthreads();

  // ---- dense K=384 in 3 phases of 128 k-cols (W0/W1 prefetched) ----
  f32x4 cd[2] = {};
  #pragma unroll
  for (int j = 0; j < 3; ++j){
    const char* Wb = (j & 1) ? W1 : W0;
    #pragma unroll
    for (int kh = 0; kh < 4; ++kh){
      int kbf = 2 * (j * 128 + kh * 32 + ko);
      int sub = (kh >= 2) ? 8192 : 0;
      int kbw = 2 * ((kh & 1) * 32 + ko);
      int orow = wo * 16 + fr;
      bf16x8 bw = *(const bf16x8*)(Wb + sub + ((orow * 128 + kbw) ^ ((orow & 7) << 4)));
      #pragma unroll
      for (int fm = 0; fm < 2; ++fm){
        int r = wn * 32 + fm * 16 + fr;
        bf16x8 af = *(const bf16x8*)(FT + ((r * 768 + kbf) ^ ((r & 7) << 4)));
        cd[fm] = mfma16(af, bw, cd[fm]);
      }
    }
    __syncthreads();
    if (j == 0) gloadW2(2, W0);
  }

  // ---- epilogue: tanh -> CL ----
  #pragma unroll
  for (int fm = 0; fm < 2; ++fm){
    int o = wo * 16 + fr;
    float bias = bc[o];
    #pragma unroll
    for (int q = 0; q < 4; ++q){
      int nn = wn * 32 + fm * 16 + ro + q;
      float e = __expf(2.f * (cd[fm][q] + bias));
      *(float*)(CL + ((nn * 256 + 4 * o) ^ ((nn & 7) << 5))) = (e - 1.f) / (e + 1.f);
    }
  }
  __syncthreads();
  {
    int row = tid >> 3, o8 = (tid & 7) * 8;
    int base = (row * 256 + 4 * o8) ^ ((row & 7) << 5);
    f32x4 c0 = *(const f32x4*)(CL + base);
    f32x4 c1 = *(const f32x4*)(CL + base + 16);
    size_t gi = ((size_t)b * NN + n0 + row) * NH + o8;
    f32x4 u0 = *(const f32x4*)&u_l[gi], u1 = *(const f32x4*)&u_l[gi + 4];
    f32x4 h0v = *(const f32x4*)&hNf_l[gi], h1v = *(const f32x4*)&hNf_l[gi + 4];
    f32x4 n0v, n1v;
    #pragma unroll
    for (int q = 0; q < 4; ++q){
      n0v[q] = u0[q] * h0v[q] + (1.f - u0[q]) * c0[q];
      n1v[q] = u1[q] * h1v[q] + (1.f - u1[q]) * c1[q];
    }
    *(f32x4*)&hNf_l[gi] = n0v; *(f32x4*)&hNf_l[gi + 4] = n1v;
    bf16x8 hb;
    #pragma unroll
    for (int q = 0; q < 4; ++q){ hb[q] = (bf16_t)n0v[q]; hb[q + 4] = (bf16_t)n1v[q]; }
    *(bf16x8*)&hN_l[gi] = hb;
    float* cr = cur + (size_t)t * NB * NN * NH + gi;
    *(f32x4*)cr = n0v; *(f32x4*)(cr + 4) = n1v;
    if (t == TSTEPS - 1){
      *(f32x4*)&fin[gi] = n0v; *(f32x4*)&fin[gi + 4] = n1v;
    }
  }
}

// ---------------- host orchestration ----------------------------------------------
extern "C" void kernel_launch(void* const* d_in, const int* in_sizes, int n_in,
                              void* d_out, int out_size, void* d_ws, size_t ws_size,
                              hipStream_t stream){
  const float* inputs = (const float*)d_in[0];
  const float* h0     = (const float*)d_in[1];
  const float* S      = (const float*)d_in[2];
  const float* W_gate = (const float*)d_in[3];
  const float* b_gate = (const float*)d_in[4];
  const float* W_c    = (const float*)d_in[5];
  const float* b_c    = (const float*)d_in[6];
  float* out = (float*)d_out;
  char* ws = (char*)d_ws;

  char*   SP  =          ws + 0;            // 1,048,576
  char*   WgP =          ws + 1048576;      // 196,608
  char*   WcP =          ws + 1245184;      // 98,304
  float*  hNf = (float*) (ws + 1343488);    // 8,388,608 (2 layers)
  bf16_t* hN  = (bf16_t*)(ws + 9732096);    // 4,194,304
  bf16_t* rhN = (bf16_t*)(ws + 13926400);   // 4,194,304
  float*  uN  = (float*) (ws + 18120704);   // 8,388,608
  bf16_t* Dx  = (bf16_t*)(ws + 26509312);   // 8,388,608
  bf16_t* rhT = (bf16_t*)(ws + 34897920);   // 4,194,304 -> end 39,092,224
  // S2f (1MB, setup-only) aliases layer-1 Dx region (first written at p=1)
  float*  S2f = (float*) (ws + 26509312 + 4194304);

  k_s2f<<<dim3(1024), 256, 0, stream>>>(S, S2f);
  k_prepS<<<dim3(2048), 256, 0, stream>>>(S, S2f, SP);
  k_prepW<<<dim3(384), 256, 0, stream>>>(W_gate, WgP, 128);
  k_prepW<<<dim3(192), 256, 0, stream>>>(W_c, WcP, 64);
  k_hinit<<<dim3(1024), 256, 0, stream>>>(h0, hNf, hN);

  for (int p = 0; p <= TSTEPS; ++p){
    k_gate<<<dim3(256, 2), 512, 0, stream>>>(inputs, out + (size_t)2 * NB * NN * NH,
                                             p, hN, SP, WgP, b_gate, rhN, rhT, uN, Dx);
    k_cand<<<dim3(256, 2), 512, 0, stream>>>(inputs, p, rhN, rhT, Dx, SP, WcP, b_c,
                                             uN, hNf, hN, out);
  }
}

// Round 13
// 2194.254 us; speedup vs baseline: 1.0541x; 1.0541x over previous
//
#include <hip/hip_runtime.h>
#include <math.h>

typedef __bf16 bf16_t;
typedef bf16_t bf16x8 __attribute__((ext_vector_type(8)));
typedef bf16_t bf16x4 __attribute__((ext_vector_type(4)));
typedef float  f32x4  __attribute__((ext_vector_type(4)));
typedef unsigned long long u64_t;

#define NB 32
#define NN 512
#define NH 64
#define NF 384
#define TSTEPS 48

static __device__ __forceinline__ f32x4 mfma16(bf16x8 a, bf16x8 b, f32x4 c){
  return __builtin_amdgcn_mfma_f32_16x16x32_bf16(a, b, c, 0, 0, 0);
}
static __device__ __forceinline__ void gload16(char* lds, const char* g){
  __builtin_amdgcn_global_load_lds((const __attribute__((address_space(1))) void*)g,
                                   (__attribute__((address_space(3))) void*)lds, 16, 0, 0);
}
static __device__ __forceinline__ unsigned pack2(float a, float b){
  bf16_t x = (bf16_t)a, y = (bf16_t)b;
  unsigned short ux = __builtin_bit_cast(unsigned short, x);
  unsigned short uy = __builtin_bit_cast(unsigned short, y);
  return (unsigned)ux | ((unsigned)uy << 16);
}

// ---------------- setup kernels ---------------------------------------------------
__global__ __launch_bounds__(256) void k_s2f(const float* __restrict__ S,
                                             float* __restrict__ S2f){
  int idx = blockIdx.x * 256 + threadIdx.x;
  int n = idx >> 9, m = idx & 511;
  float acc = 0.f;
  #pragma unroll 8
  for (int k = 0; k < 512; ++k) acc += S[n * 512 + k] * S[k * 512 + m];
  S2f[idx] = acc;
}

__global__ __launch_bounds__(256) void k_prepS(const float* __restrict__ S,
                                               const float* __restrict__ S2f,
                                               char* __restrict__ dst){
  int id = blockIdx.x * 256 + threadIdx.x;       // 524288
  int r = id >> 9, k = id & 511;
  float v = (r < 512) ? S[r * 512 + k] : S2f[(r - 512) * 512 + k];
  int rt = r >> 5, rr = r & 31, kt = k >> 6, kk = k & 63;
  size_t off = ((size_t)(rt * 8 + kt)) * 4096 + (size_t)(((rr * 128 + 2 * kk)) ^ ((rr & 7) << 4));
  *(bf16_t*)(dst + off) = (bf16_t)v;
}

__global__ __launch_bounds__(256) void k_prepW(const float* __restrict__ W,
                                               char* __restrict__ dst, int OD){
  int i = blockIdx.x * 256 + threadIdx.x;
  int total = 2 * NF * OD;
  if (i >= total) return;
  int l = i / (NF * OD), rem = i - l * (NF * OD);
  int o = rem / NF, f = rem - o * NF;
  const float* Wl = W + (size_t)l * NF * OD;
  float v;
  if (f < 128)      v = Wl[f * OD + o] - Wl[(256 + f) * OD + o];
  else if (f < 256) v = Wl[f * OD + o];
  else              v = 2.f * Wl[f * OD + o];
  int kt = f >> 6, kk = f & 63;
  size_t off = (size_t)l * (6 * OD * 128) + (size_t)kt * (OD * 128)
             + (size_t)(((o * 128 + 2 * kk)) ^ ((o & 7) << 4));
  *(bf16_t*)(dst + off) = (bf16_t)v;
}

__global__ __launch_bounds__(256) void k_hinit(const float* __restrict__ h0,
                                               float* __restrict__ hNf,
                                               bf16_t* __restrict__ hN){
  size_t i = ((size_t)blockIdx.x * 256 + threadIdx.x) * 8;
  f32x4 a = *(const f32x4*)&h0[i], b = *(const f32x4*)&h0[i + 4];
  *(f32x4*)&hNf[i] = a; *(f32x4*)&hNf[i + 4] = b;
  bf16x8 v;
  #pragma unroll
  for (int q = 0; q < 4; ++q){ v[q] = (bf16_t)a[q]; v[q + 4] = (bf16_t)b[q]; }
  *(bf16x8*)&hN[i] = v;
}

// ---------------- gate kernel (R11 verbatim; grid (256,2), t = p - l) -------------
__global__ __launch_bounds__(512, 4) void k_gate(
    const float* __restrict__ inputs, const float* __restrict__ curp, int p,
    const bf16_t* __restrict__ hN, const char* __restrict__ SP,
    const char* __restrict__ WgP, const float* __restrict__ bga,
    bf16_t* __restrict__ rhN, float* __restrict__ uN, bf16_t* __restrict__ Dx)
{
  const int l = blockIdx.y;
  const int t = p - l;
  if (t < 0 || t >= TSTEPS) return;

  __shared__ char smem[81920];
  char* const A0 = smem;            char* const A1 = smem + 16384;
  char* const B0 = smem + 32768;    char* const B1 = smem + 49152;
  char* const FT = smem;            // feat 64x384 swz (49152)
  char* const W0 = smem + 49152;    // overlays B1 -> only load AFTER K-loop!
  char* const W1 = smem + 65536;
  char* const RL = smem + 49152;    // rh 64x64 bf16 (8K, after dense)
  char* const UL = smem + 57344;    // u  64x64 f32  (16K)

  const int L = blockIdx.x;                 // 256 = 8 bx x 32 b
  const int b  = (L & 7) + ((L >> 6) << 3);
  const int bx = (L >> 3) & 7;
  const int n0 = bx * 64;
  const int tid = threadIdx.x, lane = tid & 63, w = tid >> 6;
  const int fr = lane & 15, ko = (lane >> 4) * 8, ro = (lane >> 4) * 4;
  const int pp = tid >> 4, q4 = tid & 15;
  const int wr = w >> 2, wc = w & 3;        // diffusion tiling
  const int wn = w & 1, wo = w >> 1;        // dense tiling

  const float* xall = l ? curp : inputs;
  const float*  xs = xall + ((size_t)t * NB + b) * NN * NH;
  const bf16_t* hbg = hN + ((size_t)(l * NB + b)) * NN * NH;
  const char* const WgPl = WgP + (size_t)l * 98304;
  const float* const bg = bga + l * 128;
  bf16_t* const rh_l = rhN + (size_t)l * NB * NN * NH;
  float*  const u_l  = uN  + (size_t)l * NB * NN * NH;
  bf16_t* const Dx_l = Dx  + (size_t)l * NB * NN * 128;

  f32x4 acc[4][2] = {};
  f32x4 rx0[2], rx1[2]; u64_t rh0[2], rh1[2];
  char* const Abuf[2] = { A0, A1 };
  char* const Bbuf[2] = { B0, B1 };

  auto ldB = [&](int kt, int s){
    int m = kt * 64 + 2 * pp;
    const float* xr = xs + (size_t)m * NH + q4 * 4;
    rx0[s] = *(const f32x4*)xr; rx1[s] = *(const f32x4*)(xr + NH);
    const bf16_t* hr = hbg + (size_t)m * NH + q4 * 4;
    rh0[s] = *(const u64_t*)hr; rh1[s] = *(const u64_t*)(hr + NH);
  };
  auto stB = [&](int s, char* Bb){
    int mby = 4 * pp;
    #pragma unroll
    for (int i = 0; i < 4; ++i){
      int c = q4 * 4 + i;
      *(unsigned*)(Bb + ((c * 128 + mby) ^ (((c >> 2) & 7) << 4))) = pack2(rx0[s][i], rx1[s][i]);
      int c2 = c + 64;
      unsigned uh = (unsigned)((rh0[s] >> (16 * i)) & 0xffffULL)
                  | ((unsigned)((rh1[s] >> (16 * i)) & 0xffffULL) << 16);
      *(unsigned*)(Bb + ((c2 * 128 + mby) ^ (((c2 >> 2) & 7) << 4))) = uh;
    }
  };
  auto gloadA = [&](int kt, char* Ab){
    #pragma unroll
    for (int i = 0; i < 2; ++i){
      int c = w * 2 + i;                  // 16 chunks of 1KB
      int ti = c >> 2;                    // 0..3
      int rt = (ti < 2) ? (bx * 2 + ti) : (16 + bx * 2 + (ti - 2));
      gload16(Ab + c * 1024,
              SP + ((size_t)(rt * 8 + kt)) * 4096 + (c & 3) * 1024 + lane * 16);
    }
  };
  auto gloadW = [&](int j, char* Wb){
    const char* src = WgPl + (size_t)j * 16384 + (w * 64 + lane) * 16;
    gload16(Wb + w * 1024, src);
    gload16(Wb + 8192 + w * 1024, src + 8192);
  };
  auto dmm = [&](const char* Ab, const char* Bb){
    #pragma unroll
    for (int kh = 0; kh < 2; ++kh){
      int kb = 2 * (kh * 32 + ko);
      bf16x8 af[4], bf_[2];
      #pragma unroll
      for (int fm = 0; fm < 4; ++fm){
        int r = wr * 64 + fm * 16 + fr;
        af[fm] = *(const bf16x8*)(Ab + (r >> 5) * 4096 + ((((r & 31) * 128 + kb)) ^ ((r & 7) << 4)));
      }
      #pragma unroll
      for (int fc = 0; fc < 2; ++fc){
        int c = wc * 32 + fc * 16 + fr;
        bf_[fc] = *(const bf16x8*)(Bb + ((c * 128 + kb) ^ (((c >> 2) & 7) << 4)));
      }
      #pragma unroll
      for (int fm = 0; fm < 4; ++fm)
        #pragma unroll
        for (int fc = 0; fc < 2; ++fc)
          acc[fm][fc] = mfma16(af[fm], bf_[fc], acc[fm][fc]);
    }
  };

  // prologue: DMA-first (NO W prefetch here: W0 aliases B1)
  gloadA(0, A0);
  ldB(0, 0); stB(0, B0);
  ldB(1, 1);
  __syncthreads();

  // K-loop: 1 barrier per iteration, DMA issued before VALU staging
  #pragma unroll
  for (int kt = 0; kt < 8; ++kt){
    if (kt < 7){
      gloadA(kt + 1, Abuf[(kt + 1) & 1]);
      stB((kt + 1) & 1, Bbuf[(kt + 1) & 1]);
    }
    dmm(Abuf[kt & 1], Bbuf[kt & 1]);
    __syncthreads();
    if (kt < 6) ldB(kt + 2, (kt + 2) & 1);
  }

  // W chunks 0,1 prefetch — B1 now dead; in flight during feat fill/scatter
  gloadW(0, W0); gloadW(1, W1);

  // ---- feat fill (x,h -> cols 0..127) + diffusion scatter (128..383) ----
  #pragma unroll
  for (int s = 0; s < 2; ++s){
    int i = tid + s * 512;
    int row = i >> 4, c8 = (i & 15) * 8;
    char* fdst = FT + (((row * 768 + 2 * c8)) ^ ((row & 7) << 4));
    if (c8 < 64){
      const float* xr = xs + (size_t)(n0 + row) * NH + c8;
      f32x4 a = *(const f32x4*)xr, bq = *(const f32x4*)(xr + 4);
      bf16x8 v;
      #pragma unroll
      for (int q = 0; q < 4; ++q){ v[q] = (bf16_t)a[q]; v[q + 4] = (bf16_t)bq[q]; }
      *(bf16x8*)fdst = v;
    } else {
      *(bf16x8*)fdst = *(const bf16x8*)(hbg + (size_t)(n0 + row) * NH + (c8 - 64));
    }
  }
  #pragma unroll
  for (int fm = 0; fm < 4; ++fm)
    #pragma unroll
    for (int fc = 0; fc < 2; ++fc)
      #pragma unroll
      for (int q = 0; q < 4; ++q){
        int dr = wr * 64 + fm * 16 + ro + q;       // 0..127
        int nn = dr & 63;
        int col = ((dr < 64) ? 128 : 256) + wc * 32 + fc * 16 + fr;
        *(bf16_t*)(FT + (((nn * 768 + 2 * col)) ^ ((nn & 7) << 4))) = (bf16_t)acc[fm][fc][q];
      }
  __syncthreads();

  // Dx dump (x-halves of diffusion for cand reuse)
  #pragma unroll
  for (int s = 0; s < 2; ++s){
    int i = tid + s * 512;
    int row = i >> 4, d8 = (i & 15) * 8;
    int col = (d8 < 64) ? 128 + d8 : 256 + (d8 - 64);
    bf16x8 v = *(const bf16x8*)(FT + (((row * 768 + 2 * col)) ^ ((row & 7) << 4)));
    *(bf16x8*)&Dx_l[((size_t)b * NN + n0 + row) * 128 + d8] = v;
  }

  // ---- dense K=384, W double-buffer (chunks 0,1 already in flight) ----
  f32x4 gd[2][2] = {};
  #pragma unroll
  for (int j = 0; j < 6; ++j){
    const char* Wb = (j & 1) ? W1 : W0;
    #pragma unroll
    for (int kh = 0; kh < 2; ++kh){
      int kbf = 2 * (j * 64 + kh * 32 + ko);
      int kbw = 2 * (kh * 32 + ko);
      bf16x8 af[2];
      #pragma unroll
      for (int fm = 0; fm < 2; ++fm){
        int r = wn * 32 + fm * 16 + fr;
        af[fm] = *(const bf16x8*)(FT + ((r * 768 + kbf) ^ ((r & 7) << 4)));
      }
      #pragma unroll
      for (int fo = 0; fo < 2; ++fo){
        int orow = wo * 32 + fo * 16 + fr;
        bf16x8 bw = *(const bf16x8*)(Wb + ((orow * 128 + kbw) ^ ((orow & 7) << 4)));
        #pragma unroll
        for (int fm = 0; fm < 2; ++fm)
          gd[fm][fo] = mfma16(af[fm], bw, gd[fm][fo]);
      }
    }
    __syncthreads();
    if (j < 4) gloadW(j + 2, (j & 1) ? W1 : W0);
  }

  // ---- epilogue: sigmoid -> rh / u tiles in LDS ----
  #pragma unroll
  for (int fm = 0; fm < 2; ++fm)
    #pragma unroll
    for (int fo = 0; fo < 2; ++fo){
      int o = wo * 32 + fo * 16 + fr;
      float bias = bg[o];
      #pragma unroll
      for (int q = 0; q < 4; ++q){
        int nn = wn * 32 + fm * 16 + ro + q;
        float g = 1.f / (1.f + __expf(-(gd[fm][fo][q] + bias)));
        if (o < 64){
          float hv = (float)*(const bf16_t*)(FT + (((nn * 768 + 2 * (64 + o))) ^ ((nn & 7) << 4)));
          *(bf16_t*)(RL + ((nn * 128 + 2 * o) ^ ((nn & 7) << 4))) = (bf16_t)(g * hv);
        } else {
          *(float*)(UL + ((nn * 256 + 4 * (o - 64)) ^ ((nn & 7) << 5))) = g;
        }
      }
    }
  __syncthreads();
  {
    int row = tid >> 3, o8 = (tid & 7) * 8;
    bf16x8 v = *(const bf16x8*)(RL + ((row * 128 + 2 * o8) ^ ((row & 7) << 4)));
    *(bf16x8*)&rh_l[((size_t)b * NN + n0 + row) * NH + o8] = v;
    int base = (row * 256 + 4 * o8) ^ ((row & 7) << 5);
    f32x4 u0 = *(const f32x4*)(UL + base);
    f32x4 u1 = *(const f32x4*)(UL + base + 16);
    size_t gi = ((size_t)b * NN + n0 + row) * NH + o8;
    *(f32x4*)&u_l[gi] = u0; *(f32x4*)&u_l[gi + 4] = u1;
  }
}

// ---------------- candidate kernel (R11 body, 3-phase dense) ----------------------
__global__ __launch_bounds__(512, 4) void k_cand(
    const float* __restrict__ inputs, int p,
    const bf16_t* __restrict__ rhN, const bf16_t* __restrict__ Dx,
    const char* __restrict__ SP, const char* __restrict__ WcP,
    const float* __restrict__ bca, const float* __restrict__ uN,
    float* __restrict__ hNf, bf16_t* __restrict__ hN,
    float* __restrict__ outp)
{
  const int l = blockIdx.y;
  const int t = p - l;
  if (t < 0 || t >= TSTEPS) return;

  __shared__ char smem[81920];
  char* const A0 = smem;            char* const A1 = smem + 16384;
  char* const B0 = smem + 32768;    char* const B1 = smem + 40960;
  char* const FT = smem;            // feat 64x384 swz (49152)
  char* const W0 = smem + 49152;    char* const W1 = smem + 65536;  // 16KB each
  char* const CL = smem + 49152;    // c 64x64 f32 (16K, after dense)

  const int L = blockIdx.x;
  const int b  = (L & 7) + ((L >> 6) << 3);
  const int bx = (L >> 3) & 7;
  const int n0 = bx * 64;
  const int tid = threadIdx.x, lane = tid & 63, w = tid >> 6;
  const int fr = lane & 15, ko = (lane >> 4) * 8, ro = (lane >> 4) * 4;
  const int pp = tid >> 4, q4 = tid & 15;
  const int wr = w >> 2, wc = w & 3;
  const int wn = w & 1, wo = w >> 1;

  float* const cur = outp + (size_t)2 * NB * NN * NH;
  const float* xall = l ? cur : inputs;
  const float*  xs = xall + ((size_t)t * NB + b) * NN * NH;
  const bf16_t* rbg = rhN + ((size_t)(l * NB + b)) * NN * NH;
  const char* const WcPl = WcP + (size_t)l * 49152;
  const float* const bc = bca + l * 64;
  const bf16_t* const Dx_l = Dx + (size_t)l * NB * NN * 128;
  const float* const u_l = uN + (size_t)l * NB * NN * NH;
  float*  const hNf_l = hNf + (size_t)l * NB * NN * NH;
  bf16_t* const hN_l  = hN  + (size_t)l * NB * NN * NH;
  float* const fin = outp + (size_t)l * NB * NN * NH;

  f32x4 ca[4] = {};
  u64_t rh0[2], rh1[2];
  char* const Abuf[2] = { A0, A1 };
  char* const Bbuf[2] = { B0, B1 };

  auto ldB = [&](int kt, int s){
    int m = kt * 64 + 2 * pp;
    const bf16_t* rr = rbg + (size_t)m * NH + q4 * 4;
    rh0[s] = *(const u64_t*)rr; rh1[s] = *(const u64_t*)(rr + NH);
  };
  auto stB = [&](int s, char* Bb){
    int mby = 4 * pp;
    #pragma unroll
    for (int i = 0; i < 4; ++i){
      int c = q4 * 4 + i;
      unsigned u = (unsigned)((rh0[s] >> (16 * i)) & 0xffffULL)
                 | ((unsigned)((rh1[s] >> (16 * i)) & 0xffffULL) << 16);
      *(unsigned*)(Bb + ((c * 128 + mby) ^ (((c >> 2) & 7) << 4))) = u;
    }
  };
  auto gloadA = [&](int kt, char* Ab){
    #pragma unroll
    for (int i = 0; i < 2; ++i){
      int c = w * 2 + i;
      int ti = c >> 2;
      int rt = (ti < 2) ? (bx * 2 + ti) : (16 + bx * 2 + (ti - 2));
      gload16(Ab + c * 1024,
              SP + ((size_t)(rt * 8 + kt)) * 4096 + (c & 3) * 1024 + lane * 16);
    }
  };
  // W chunk-pair j (prep chunks 2j, 2j+1) -> 16KB buffer
  auto gloadW2 = [&](int j, char* Wb){
    const char* src = WcPl + (size_t)(2 * j) * 8192 + (w * 64 + lane) * 16;
    gload16(Wb + w * 1024, src);
    gload16(Wb + 8192 + w * 1024, src + 8192);
  };
  auto cmm = [&](const char* Ab, const char* Bb){
    #pragma unroll
    for (int kh = 0; kh < 2; ++kh){
      int kb = 2 * (kh * 32 + ko);
      int c = wc * 16 + fr;
      bf16x8 bf_ = *(const bf16x8*)(Bb + ((c * 128 + kb) ^ (((c >> 2) & 7) << 4)));
      #pragma unroll
      for (int fm = 0; fm < 4; ++fm){
        int r = wr * 64 + fm * 16 + fr;
        bf16x8 af = *(const bf16x8*)(Ab + (r >> 5) * 4096 + ((((r & 31) * 128 + kb)) ^ ((r & 7) << 4)));
        ca[fm] = mfma16(af, bf_, ca[fm]);
      }
    }
  };

  gloadA(0, A0);
  gloadW2(0, W0); gloadW2(1, W1);   // safe: W regions don't alias A/B here
  ldB(0, 0); stB(0, B0);
  ldB(1, 1);
  __syncthreads();

  #pragma unroll
  for (int kt = 0; kt < 8; ++kt){
    if (kt < 7){
      gloadA(kt + 1, Abuf[(kt + 1) & 1]);
      stB((kt + 1) & 1, Bbuf[(kt + 1) & 1]);
    }
    cmm(Abuf[kt & 1], Bbuf[kt & 1]);
    __syncthreads();
    if (kt < 6) ldB(kt + 2, (kt + 2) & 1);
  }

  // ---- feat fill: x(0-63), rh(64-127), Dx(128-191/256-319) + scatter(192/320) ----
  #pragma unroll
  for (int s = 0; s < 2; ++s){
    int i = tid + s * 512;
    int row = i >> 4, c8 = (i & 15) * 8;
    char* fdst = FT + (((row * 768 + 2 * c8)) ^ ((row & 7) << 4));
    if (c8 < 64){
      const float* xr = xs + (size_t)(n0 + row) * NH + c8;
      f32x4 a = *(const f32x4*)xr, bq = *(const f32x4*)(xr + 4);
      bf16x8 v;
      #pragma unroll
      for (int q = 0; q < 4; ++q){ v[q] = (bf16_t)a[q]; v[q + 4] = (bf16_t)bq[q]; }
      *(bf16x8*)fdst = v;
    } else {
      *(bf16x8*)fdst = *(const bf16x8*)(rbg + (size_t)(n0 + row) * NH + (c8 - 64));
    }
    int col = (c8 < 64) ? 128 + c8 : 256 + (c8 - 64);
    bf16x8 dv = *(const bf16x8*)&Dx_l[((size_t)b * NN + n0 + row) * 128 + c8];
    *(bf16x8*)(FT + (((row * 768 + 2 * col)) ^ ((row & 7) << 4))) = dv;
  }
  #pragma unroll
  for (int fm = 0; fm < 4; ++fm)
    #pragma unroll
    for (int q = 0; q < 4; ++q){
      int dr = wr * 64 + fm * 16 + ro + q;
      int nn = dr & 63;
      int col = ((dr < 64) ? 192 : 320) + wc * 16 + fr;
      *(bf16_t*)(FT + (((nn * 768 + 2 * col)) ^ ((nn & 7) << 4))) = (bf16_t)ca[fm][q];
    }
  __syncthreads();

  // ---- dense K=384 in 3 phases of 128 k-cols (W0/W1 prefetched at prologue) ----
  f32x4 cd[2] = {};
  #pragma unroll
  for (int j = 0; j < 3; ++j){
    const char* Wb = (j & 1) ? W1 : W0;
    #pragma unroll
    for (int kh = 0; kh < 4; ++kh){
      int kbf = 2 * (j * 128 + kh * 32 + ko);
      int sub = (kh >= 2) ? 8192 : 0;
      int kbw = 2 * ((kh & 1) * 32 + ko);
      int orow = wo * 16 + fr;
      bf16x8 bw = *(const bf16x8*)(Wb + sub + ((orow * 128 + kbw) ^ ((orow & 7) << 4)));
      #pragma unroll
      for (int fm = 0; fm < 2; ++fm){
        int r = wn * 32 + fm * 16 + fr;
        bf16x8 af = *(const bf16x8*)(FT + ((r * 768 + kbf) ^ ((r & 7) << 4)));
        cd[fm] = mfma16(af, bw, cd[fm]);
      }
    }
    __syncthreads();
    if (j == 0) gloadW2(2, W0);   // chunks 4,5 -> W0; drained by j=1's barrier
  }

  // ---- epilogue: tanh -> CL ----
  #pragma unroll
  for (int fm = 0; fm < 2; ++fm){
    int o = wo * 16 + fr;
    float bias = bc[o];
    #pragma unroll
    for (int q = 0; q < 4; ++q){
      int nn = wn * 32 + fm * 16 + ro + q;
      float e = __expf(2.f * (cd[fm][q] + bias));
      *(float*)(CL + ((nn * 256 + 4 * o) ^ ((nn & 7) << 5))) = (e - 1.f) / (e + 1.f);
    }
  }
  __syncthreads();
  {
    int row = tid >> 3, o8 = (tid & 7) * 8;
    int base = (row * 256 + 4 * o8) ^ ((row & 7) << 5);
    f32x4 c0 = *(const f32x4*)(CL + base);
    f32x4 c1 = *(const f32x4*)(CL + base + 16);
    size_t gi = ((size_t)b * NN + n0 + row) * NH + o8;
    f32x4 u0 = *(const f32x4*)&u_l[gi], u1 = *(const f32x4*)&u_l[gi + 4];
    f32x4 h0v = *(const f32x4*)&hNf_l[gi], h1v = *(const f32x4*)&hNf_l[gi + 4];
    f32x4 n0v, n1v;
    #pragma unroll
    for (int q = 0; q < 4; ++q){
      n0v[q] = u0[q] * h0v[q] + (1.f - u0[q]) * c0[q];
      n1v[q] = u1[q] * h1v[q] + (1.f - u1[q]) * c1[q];
    }
    *(f32x4*)&hNf_l[gi] = n0v; *(f32x4*)&hNf_l[gi + 4] = n1v;
    bf16x8 hb;
    #pragma unroll
    for (int q = 0; q < 4; ++q){ hb[q] = (bf16_t)n0v[q]; hb[q + 4] = (bf16_t)n1v[q]; }
    *(bf16x8*)&hN_l[gi] = hb;
    float* cr = cur + (size_t)t * NB * NN * NH + gi;
    *(f32x4*)cr = n0v; *(f32x4*)(cr + 4) = n1v;
    if (t == TSTEPS - 1){
      *(f32x4*)&fin[gi] = n0v; *(f32x4*)&fin[gi + 4] = n1v;
    }
  }
}

// ---------------- host orchestration ----------------------------------------------
extern "C" void kernel_launch(void* const* d_in, const int* in_sizes, int n_in,
                              void* d_out, int out_size, void* d_ws, size_t ws_size,
                              hipStream_t stream){
  const float* inputs = (const float*)d_in[0];
  const float* h0     = (const float*)d_in[1];
  const float* S      = (const float*)d_in[2];
  const float* W_gate = (const float*)d_in[3];
  const float* b_gate = (const float*)d_in[4];
  const float* W_c    = (const float*)d_in[5];
  const float* b_c    = (const float*)d_in[6];
  float* out = (float*)d_out;
  char* ws = (char*)d_ws;

  char*   SP  =          ws + 0;            // 1,048,576
  char*   WgP =          ws + 1048576;      // 196,608
  char*   WcP =          ws + 1245184;      // 98,304
  float*  hNf = (float*) (ws + 1343488);    // 8,388,608 (2 layers)
  bf16_t* hN  = (bf16_t*)(ws + 9732096);    // 4,194,304
  bf16_t* rhN = (bf16_t*)(ws + 13926400);   // 4,194,304
  float*  uN  = (float*) (ws + 18120704);   // 8,388,608
  bf16_t* Dx  = (bf16_t*)(ws + 26509312);   // 8,388,608 -> end 34,897,920
  // S2f (1MB, setup-only) aliases layer-1 Dx region (first written at p=1)
  float*  S2f = (float*) (ws + 26509312 + 4194304);

  k_s2f<<<dim3(1024), 256, 0, stream>>>(S, S2f);
  k_prepS<<<dim3(2048), 256, 0, stream>>>(S, S2f, SP);
  k_prepW<<<dim3(384), 256, 0, stream>>>(W_gate, WgP, 128);
  k_prepW<<<dim3(192), 256, 0, stream>>>(W_c, WcP, 64);
  k_hinit<<<dim3(1024), 256, 0, stream>>>(h0, hNf, hN);

  for (int p = 0; p <= TSTEPS; ++p){
    k_gate<<<dim3(256, 2), 512, 0, stream>>>(inputs, out + (size_t)2 * NB * NN * NH,
                                             p, hN, SP, WgP, b_gate, rhN, uN, Dx);
    k_cand<<<dim3(256, 2), 512, 0, stream>>>(inputs, p, rhN, Dx, SP, WcP, b_c, uN,
                                             hNf, hN, out);
  }
}

// Round 14
// 2179.650 us; speedup vs baseline: 1.0611x; 1.0067x over previous
//
#include <hip/hip_runtime.h>
#include <math.h>

typedef __bf16 bf16_t;
typedef bf16_t bf16x8 __attribute__((ext_vector_type(8)));
typedef bf16_t bf16x4 __attribute__((ext_vector_type(4)));
typedef float  f32x4  __attribute__((ext_vector_type(4)));
typedef unsigned long long u64_t;

#define NB 32
#define NN 512
#define NH 64
#define NF 384
#define TSTEPS 48

static __device__ __forceinline__ f32x4 mfma16(bf16x8 a, bf16x8 b, f32x4 c){
  return __builtin_amdgcn_mfma_f32_16x16x32_bf16(a, b, c, 0, 0, 0);
}
static __device__ __forceinline__ void gload16(char* lds, const char* g){
  __builtin_amdgcn_global_load_lds((const __attribute__((address_space(1))) void*)g,
                                   (__attribute__((address_space(3))) void*)lds, 16, 0, 0);
}
static __device__ __forceinline__ unsigned pack2(float a, float b){
  bf16_t x = (bf16_t)a, y = (bf16_t)b;
  unsigned short ux = __builtin_bit_cast(unsigned short, x);
  unsigned short uy = __builtin_bit_cast(unsigned short, y);
  return (unsigned)ux | ((unsigned)uy << 16);
}

// ---------------- setup kernels ---------------------------------------------------
__global__ __launch_bounds__(256) void k_s2f(const float* __restrict__ S,
                                             float* __restrict__ S2f){
  int idx = blockIdx.x * 256 + threadIdx.x;
  int n = idx >> 9, m = idx & 511;
  float acc = 0.f;
  #pragma unroll 8
  for (int k = 0; k < 512; ++k) acc += S[n * 512 + k] * S[k * 512 + m];
  S2f[idx] = acc;
}

__global__ __launch_bounds__(256) void k_prepS(const float* __restrict__ S,
                                               const float* __restrict__ S2f,
                                               char* __restrict__ dst){
  int id = blockIdx.x * 256 + threadIdx.x;       // 524288
  int r = id >> 9, k = id & 511;
  float v = (r < 512) ? S[r * 512 + k] : S2f[(r - 512) * 512 + k];
  int rt = r >> 5, rr = r & 31, kt = k >> 6, kk = k & 63;
  size_t off = ((size_t)(rt * 8 + kt)) * 4096 + (size_t)(((rr * 128 + 2 * kk)) ^ ((rr & 7) << 4));
  *(bf16_t*)(dst + off) = (bf16_t)v;
}

__global__ __launch_bounds__(256) void k_prepW(const float* __restrict__ W,
                                               char* __restrict__ dst, int OD){
  int i = blockIdx.x * 256 + threadIdx.x;
  int total = 2 * NF * OD;
  if (i >= total) return;
  int l = i / (NF * OD), rem = i - l * (NF * OD);
  int o = rem / NF, f = rem - o * NF;
  const float* Wl = W + (size_t)l * NF * OD;
  float v;
  if (f < 128)      v = Wl[f * OD + o] - Wl[(256 + f) * OD + o];
  else if (f < 256) v = Wl[f * OD + o];
  else              v = 2.f * Wl[f * OD + o];
  int kt = f >> 6, kk = f & 63;
  size_t off = (size_t)l * (6 * OD * 128) + (size_t)kt * (OD * 128)
             + (size_t)(((o * 128 + 2 * kk)) ^ ((o & 7) << 4));
  *(bf16_t*)(dst + off) = (bf16_t)v;
}

__global__ __launch_bounds__(256) void k_hinit(const float* __restrict__ h0,
                                               float* __restrict__ hNf,
                                               bf16_t* __restrict__ hN){
  size_t i = ((size_t)blockIdx.x * 256 + threadIdx.x) * 8;
  f32x4 a = *(const f32x4*)&h0[i], b = *(const f32x4*)&h0[i + 4];
  *(f32x4*)&hNf[i] = a; *(f32x4*)&hNf[i + 4] = b;
  bf16x8 v;
  #pragma unroll
  for (int q = 0; q < 4; ++q){ v[q] = (bf16_t)a[q]; v[q + 4] = (bf16_t)b[q]; }
  *(bf16x8*)&hN[i] = v;
}

// ---------------- gate kernel (R13 + dead-barrier removal; grid (256,2)) ----------
__global__ __launch_bounds__(512, 4) void k_gate(
    const float* __restrict__ inputs, const float* __restrict__ curp, int p,
    const bf16_t* __restrict__ hN, const char* __restrict__ SP,
    const char* __restrict__ WgP, const float* __restrict__ bga,
    bf16_t* __restrict__ rhN, float* __restrict__ uN, bf16_t* __restrict__ Dx)
{
  const int l = blockIdx.y;
  const int t = p - l;
  if (t < 0 || t >= TSTEPS) return;

  __shared__ char smem[81920];
  char* const A0 = smem;            char* const A1 = smem + 16384;
  char* const B0 = smem + 32768;    char* const B1 = smem + 49152;
  char* const FT = smem;            // feat 64x384 swz (49152)
  char* const W0 = smem + 49152;    // overlays B1 -> only load AFTER K-loop!
  char* const W1 = smem + 65536;
  char* const RL = smem + 49152;    // rh 64x64 bf16 (8K, after dense)
  char* const UL = smem + 57344;    // u  64x64 f32  (16K)

  const int L = blockIdx.x;                 // 256 = 8 bx x 32 b
  const int b  = (L & 7) + ((L >> 6) << 3);
  const int bx = (L >> 3) & 7;
  const int n0 = bx * 64;
  const int tid = threadIdx.x, lane = tid & 63, w = tid >> 6;
  const int fr = lane & 15, ko = (lane >> 4) * 8, ro = (lane >> 4) * 4;
  const int pp = tid >> 4, q4 = tid & 15;
  const int wr = w >> 2, wc = w & 3;        // diffusion tiling
  const int wn = w & 1, wo = w >> 1;        // dense tiling

  const float* xall = l ? curp : inputs;
  const float*  xs = xall + ((size_t)t * NB + b) * NN * NH;
  const bf16_t* hbg = hN + ((size_t)(l * NB + b)) * NN * NH;
  const char* const WgPl = WgP + (size_t)l * 98304;
  const float* const bg = bga + l * 128;
  bf16_t* const rh_l = rhN + (size_t)l * NB * NN * NH;
  float*  const u_l  = uN  + (size_t)l * NB * NN * NH;
  bf16_t* const Dx_l = Dx  + (size_t)l * NB * NN * 128;

  f32x4 acc[4][2] = {};
  f32x4 rx0[2], rx1[2]; u64_t rh0[2], rh1[2];
  char* const Abuf[2] = { A0, A1 };
  char* const Bbuf[2] = { B0, B1 };

  auto ldB = [&](int kt, int s){
    int m = kt * 64 + 2 * pp;
    const float* xr = xs + (size_t)m * NH + q4 * 4;
    rx0[s] = *(const f32x4*)xr; rx1[s] = *(const f32x4*)(xr + NH);
    const bf16_t* hr = hbg + (size_t)m * NH + q4 * 4;
    rh0[s] = *(const u64_t*)hr; rh1[s] = *(const u64_t*)(hr + NH);
  };
  auto stB = [&](int s, char* Bb){
    int mby = 4 * pp;
    #pragma unroll
    for (int i = 0; i < 4; ++i){
      int c = q4 * 4 + i;
      *(unsigned*)(Bb + ((c * 128 + mby) ^ (((c >> 2) & 7) << 4))) = pack2(rx0[s][i], rx1[s][i]);
      int c2 = c + 64;
      unsigned uh = (unsigned)((rh0[s] >> (16 * i)) & 0xffffULL)
                  | ((unsigned)((rh1[s] >> (16 * i)) & 0xffffULL) << 16);
      *(unsigned*)(Bb + ((c2 * 128 + mby) ^ (((c2 >> 2) & 7) << 4))) = uh;
    }
  };
  auto gloadA = [&](int kt, char* Ab){
    #pragma unroll
    for (int i = 0; i < 2; ++i){
      int c = w * 2 + i;                  // 16 chunks of 1KB
      int ti = c >> 2;                    // 0..3
      int rt = (ti < 2) ? (bx * 2 + ti) : (16 + bx * 2 + (ti - 2));
      gload16(Ab + c * 1024,
              SP + ((size_t)(rt * 8 + kt)) * 4096 + (c & 3) * 1024 + lane * 16);
    }
  };
  auto gloadW = [&](int j, char* Wb){
    const char* src = WgPl + (size_t)j * 16384 + (w * 64 + lane) * 16;
    gload16(Wb + w * 1024, src);
    gload16(Wb + 8192 + w * 1024, src + 8192);
  };
  auto dmm = [&](const char* Ab, const char* Bb){
    #pragma unroll
    for (int kh = 0; kh < 2; ++kh){
      int kb = 2 * (kh * 32 + ko);
      bf16x8 af[4], bf_[2];
      #pragma unroll
      for (int fm = 0; fm < 4; ++fm){
        int r = wr * 64 + fm * 16 + fr;
        af[fm] = *(const bf16x8*)(Ab + (r >> 5) * 4096 + ((((r & 31) * 128 + kb)) ^ ((r & 7) << 4)));
      }
      #pragma unroll
      for (int fc = 0; fc < 2; ++fc){
        int c = wc * 32 + fc * 16 + fr;
        bf_[fc] = *(const bf16x8*)(Bb + ((c * 128 + kb) ^ (((c >> 2) & 7) << 4)));
      }
      #pragma unroll
      for (int fm = 0; fm < 4; ++fm)
        #pragma unroll
        for (int fc = 0; fc < 2; ++fc)
          acc[fm][fc] = mfma16(af[fm], bf_[fc], acc[fm][fc]);
    }
  };

  // prologue: DMA-first (NO W prefetch here: W0 aliases B1)
  gloadA(0, A0);
  ldB(0, 0); stB(0, B0);
  ldB(1, 1);
  __syncthreads();

  // K-loop: 1 barrier per iteration, DMA issued before VALU staging
  #pragma unroll
  for (int kt = 0; kt < 8; ++kt){
    if (kt < 7){
      gloadA(kt + 1, Abuf[(kt + 1) & 1]);
      stB((kt + 1) & 1, Bbuf[(kt + 1) & 1]);
    }
    dmm(Abuf[kt & 1], Bbuf[kt & 1]);
    __syncthreads();
    if (kt < 6) ldB(kt + 2, (kt + 2) & 1);
  }

  // W chunks 0,1 prefetch — B1 now dead; in flight during feat fill/scatter
  gloadW(0, W0); gloadW(1, W1);

  // ---- feat fill (x,h -> cols 0..127) + diffusion scatter (128..383) ----
  #pragma unroll
  for (int s = 0; s < 2; ++s){
    int i = tid + s * 512;
    int row = i >> 4, c8 = (i & 15) * 8;
    char* fdst = FT + (((row * 768 + 2 * c8)) ^ ((row & 7) << 4));
    if (c8 < 64){
      const float* xr = xs + (size_t)(n0 + row) * NH + c8;
      f32x4 a = *(const f32x4*)xr, bq = *(const f32x4*)(xr + 4);
      bf16x8 v;
      #pragma unroll
      for (int q = 0; q < 4; ++q){ v[q] = (bf16_t)a[q]; v[q + 4] = (bf16_t)bq[q]; }
      *(bf16x8*)fdst = v;
    } else {
      *(bf16x8*)fdst = *(const bf16x8*)(hbg + (size_t)(n0 + row) * NH + (c8 - 64));
    }
  }
  #pragma unroll
  for (int fm = 0; fm < 4; ++fm)
    #pragma unroll
    for (int fc = 0; fc < 2; ++fc)
      #pragma unroll
      for (int q = 0; q < 4; ++q){
        int dr = wr * 64 + fm * 16 + ro + q;       // 0..127
        int nn = dr & 63;
        int col = ((dr < 64) ? 128 : 256) + wc * 32 + fc * 16 + fr;
        *(bf16_t*)(FT + (((nn * 768 + 2 * col)) ^ ((nn & 7) << 4))) = (bf16_t)acc[fm][fc][q];
      }
  __syncthreads();

  // Dx dump (x-halves of diffusion for cand reuse)
  #pragma unroll
  for (int s = 0; s < 2; ++s){
    int i = tid + s * 512;
    int row = i >> 4, d8 = (i & 15) * 8;
    int col = (d8 < 64) ? 128 + d8 : 256 + (d8 - 64);
    bf16x8 v = *(const bf16x8*)(FT + (((row * 768 + 2 * col)) ^ ((row & 7) << 4)));
    *(bf16x8*)&Dx_l[((size_t)b * NN + n0 + row) * 128 + d8] = v;
  }

  // ---- dense K=384, W double-buffer (chunks 0,1 already in flight) ----
  // barrier after j is needed only before a reload targeting the buffer read at j
  // (j<4) or before the epilogue's RL/UL overwrite (j=5). j=4's barrier is dead.
  f32x4 gd[2][2] = {};
  #pragma unroll
  for (int j = 0; j < 6; ++j){
    const char* Wb = (j & 1) ? W1 : W0;
    #pragma unroll
    for (int kh = 0; kh < 2; ++kh){
      int kbf = 2 * (j * 64 + kh * 32 + ko);
      int kbw = 2 * (kh * 32 + ko);
      bf16x8 af[2];
      #pragma unroll
      for (int fm = 0; fm < 2; ++fm){
        int r = wn * 32 + fm * 16 + fr;
        af[fm] = *(const bf16x8*)(FT + ((r * 768 + kbf) ^ ((r & 7) << 4)));
      }
      #pragma unroll
      for (int fo = 0; fo < 2; ++fo){
        int orow = wo * 32 + fo * 16 + fr;
        bf16x8 bw = *(const bf16x8*)(Wb + ((orow * 128 + kbw) ^ ((orow & 7) << 4)));
        #pragma unroll
        for (int fm = 0; fm < 2; ++fm)
          gd[fm][fo] = mfma16(af[fm], bw, gd[fm][fo]);
      }
    }
    if (j != 4) __syncthreads();
    if (j < 4) gloadW(j + 2, (j & 1) ? W1 : W0);
  }

  // ---- epilogue: sigmoid -> rh / u tiles in LDS ----
  #pragma unroll
  for (int fm = 0; fm < 2; ++fm)
    #pragma unroll
    for (int fo = 0; fo < 2; ++fo){
      int o = wo * 32 + fo * 16 + fr;
      float bias = bg[o];
      #pragma unroll
      for (int q = 0; q < 4; ++q){
        int nn = wn * 32 + fm * 16 + ro + q;
        float g = 1.f / (1.f + __expf(-(gd[fm][fo][q] + bias)));
        if (o < 64){
          float hv = (float)*(const bf16_t*)(FT + (((nn * 768 + 2 * (64 + o))) ^ ((nn & 7) << 4)));
          *(bf16_t*)(RL + ((nn * 128 + 2 * o) ^ ((nn & 7) << 4))) = (bf16_t)(g * hv);
        } else {
          *(float*)(UL + ((nn * 256 + 4 * (o - 64)) ^ ((nn & 7) << 5))) = g;
        }
      }
    }
  __syncthreads();
  {
    int row = tid >> 3, o8 = (tid & 7) * 8;
    bf16x8 v = *(const bf16x8*)(RL + ((row * 128 + 2 * o8) ^ ((row & 7) << 4)));
    *(bf16x8*)&rh_l[((size_t)b * NN + n0 + row) * NH + o8] = v;
    int base = (row * 256 + 4 * o8) ^ ((row & 7) << 5);
    f32x4 u0 = *(const f32x4*)(UL + base);
    f32x4 u1 = *(const f32x4*)(UL + base + 16);
    size_t gi = ((size_t)b * NN + n0 + row) * NH + o8;
    *(f32x4*)&u_l[gi] = u0; *(f32x4*)&u_l[gi + 4] = u1;
  }
}

// ---------------- candidate kernel (R13 verbatim: 3-phase dense) ------------------
__global__ __launch_bounds__(512, 4) void k_cand(
    const float* __restrict__ inputs, int p,
    const bf16_t* __restrict__ rhN, const bf16_t* __restrict__ Dx,
    const char* __restrict__ SP, const char* __restrict__ WcP,
    const float* __restrict__ bca, const float* __restrict__ uN,
    float* __restrict__ hNf, bf16_t* __restrict__ hN,
    float* __restrict__ outp)
{
  const int l = blockIdx.y;
  const int t = p - l;
  if (t < 0 || t >= TSTEPS) return;

  __shared__ char smem[81920];
  char* const A0 = smem;            char* const A1 = smem + 16384;
  char* const B0 = smem + 32768;    char* const B1 = smem + 40960;
  char* const FT = smem;            // feat 64x384 swz (49152)
  char* const W0 = smem + 49152;    char* const W1 = smem + 65536;  // 16KB each
  char* const CL = smem + 49152;    // c 64x64 f32 (16K, after dense)

  const int L = blockIdx.x;
  const int b  = (L & 7) + ((L >> 6) << 3);
  const int bx = (L >> 3) & 7;
  const int n0 = bx * 64;
  const int tid = threadIdx.x, lane = tid & 63, w = tid >> 6;
  const int fr = lane & 15, ko = (lane >> 4) * 8, ro = (lane >> 4) * 4;
  const int pp = tid >> 4, q4 = tid & 15;
  const int wr = w >> 2, wc = w & 3;
  const int wn = w & 1, wo = w >> 1;

  float* const cur = outp + (size_t)2 * NB * NN * NH;
  const float* xall = l ? cur : inputs;
  const float*  xs = xall + ((size_t)t * NB + b) * NN * NH;
  const bf16_t* rbg = rhN + ((size_t)(l * NB + b)) * NN * NH;
  const char* const WcPl = WcP + (size_t)l * 49152;
  const float* const bc = bca + l * 64;
  const bf16_t* const Dx_l = Dx + (size_t)l * NB * NN * 128;
  const float* const u_l = uN + (size_t)l * NB * NN * NH;
  float*  const hNf_l = hNf + (size_t)l * NB * NN * NH;
  bf16_t* const hN_l  = hN  + (size_t)l * NB * NN * NH;
  float* const fin = outp + (size_t)l * NB * NN * NH;

  f32x4 ca[4] = {};
  u64_t rh0[2], rh1[2];
  char* const Abuf[2] = { A0, A1 };
  char* const Bbuf[2] = { B0, B1 };

  auto ldB = [&](int kt, int s){
    int m = kt * 64 + 2 * pp;
    const bf16_t* rr = rbg + (size_t)m * NH + q4 * 4;
    rh0[s] = *(const u64_t*)rr; rh1[s] = *(const u64_t*)(rr + NH);
  };
  auto stB = [&](int s, char* Bb){
    int mby = 4 * pp;
    #pragma unroll
    for (int i = 0; i < 4; ++i){
      int c = q4 * 4 + i;
      unsigned u = (unsigned)((rh0[s] >> (16 * i)) & 0xffffULL)
                 | ((unsigned)((rh1[s] >> (16 * i)) & 0xffffULL) << 16);
      *(unsigned*)(Bb + ((c * 128 + mby) ^ (((c >> 2) & 7) << 4))) = u;
    }
  };
  auto gloadA = [&](int kt, char* Ab){
    #pragma unroll
    for (int i = 0; i < 2; ++i){
      int c = w * 2 + i;
      int ti = c >> 2;
      int rt = (ti < 2) ? (bx * 2 + ti) : (16 + bx * 2 + (ti - 2));
      gload16(Ab + c * 1024,
              SP + ((size_t)(rt * 8 + kt)) * 4096 + (c & 3) * 1024 + lane * 16);
    }
  };
  // W chunk-pair j (prep chunks 2j, 2j+1) -> 16KB buffer
  auto gloadW2 = [&](int j, char* Wb){
    const char* src = WcPl + (size_t)(2 * j) * 8192 + (w * 64 + lane) * 16;
    gload16(Wb + w * 1024, src);
    gload16(Wb + 8192 + w * 1024, src + 8192);
  };
  auto cmm = [&](const char* Ab, const char* Bb){
    #pragma unroll
    for (int kh = 0; kh < 2; ++kh){
      int kb = 2 * (kh * 32 + ko);
      int c = wc * 16 + fr;
      bf16x8 bf_ = *(const bf16x8*)(Bb + ((c * 128 + kb) ^ (((c >> 2) & 7) << 4)));
      #pragma unroll
      for (int fm = 0; fm < 4; ++fm){
        int r = wr * 64 + fm * 16 + fr;
        bf16x8 af = *(const bf16x8*)(Ab + (r >> 5) * 4096 + ((((r & 31) * 128 + kb)) ^ ((r & 7) << 4)));
        ca[fm] = mfma16(af, bf_, ca[fm]);
      }
    }
  };

  gloadA(0, A0);
  gloadW2(0, W0); gloadW2(1, W1);   // safe: W regions don't alias A/B here
  ldB(0, 0); stB(0, B0);
  ldB(1, 1);
  __syncthreads();

  #pragma unroll
  for (int kt = 0; kt < 8; ++kt){
    if (kt < 7){
      gloadA(kt + 1, Abuf[(kt + 1) & 1]);
      stB((kt + 1) & 1, Bbuf[(kt + 1) & 1]);
    }
    cmm(Abuf[kt & 1], Bbuf[kt & 1]);
    __syncthreads();
    if (kt < 6) ldB(kt + 2, (kt + 2) & 1);
  }

  // ---- feat fill: x(0-63), rh(64-127), Dx(128-191/256-319) + scatter(192/320) ----
  #pragma unroll
  for (int s = 0; s < 2; ++s){
    int i = tid + s * 512;
    int row = i >> 4, c8 = (i & 15) * 8;
    char* fdst = FT + (((row * 768 + 2 * c8)) ^ ((row & 7) << 4));
    if (c8 < 64){
      const float* xr = xs + (size_t)(n0 + row) * NH + c8;
      f32x4 a = *(const f32x4*)xr, bq = *(const f32x4*)(xr + 4);
      bf16x8 v;
      #pragma unroll
      for (int q = 0; q < 4; ++q){ v[q] = (bf16_t)a[q]; v[q + 4] = (bf16_t)bq[q]; }
      *(bf16x8*)fdst = v;
    } else {
      *(bf16x8*)fdst = *(const bf16x8*)(rbg + (size_t)(n0 + row) * NH + (c8 - 64));
    }
    int col = (c8 < 64) ? 128 + c8 : 256 + (c8 - 64);
    bf16x8 dv = *(const bf16x8*)&Dx_l[((size_t)b * NN + n0 + row) * 128 + c8];
    *(bf16x8*)(FT + (((row * 768 + 2 * col)) ^ ((row & 7) << 4))) = dv;
  }
  #pragma unroll
  for (int fm = 0; fm < 4; ++fm)
    #pragma unroll
    for (int q = 0; q < 4; ++q){
      int dr = wr * 64 + fm * 16 + ro + q;
      int nn = dr & 63;
      int col = ((dr < 64) ? 192 : 320) + wc * 16 + fr;
      *(bf16_t*)(FT + (((nn * 768 + 2 * col)) ^ ((nn & 7) << 4))) = (bf16_t)ca[fm][q];
    }
  __syncthreads();

  // ---- dense K=384 in 3 phases of 128 k-cols (W0/W1 prefetched at prologue) ----
  f32x4 cd[2] = {};
  #pragma unroll
  for (int j = 0; j < 3; ++j){
    const char* Wb = (j & 1) ? W1 : W0;
    #pragma unroll
    for (int kh = 0; kh < 4; ++kh){
      int kbf = 2 * (j * 128 + kh * 32 + ko);
      int sub = (kh >= 2) ? 8192 : 0;
      int kbw = 2 * ((kh & 1) * 32 + ko);
      int orow = wo * 16 + fr;
      bf16x8 bw = *(const bf16x8*)(Wb + sub + ((orow * 128 + kbw) ^ ((orow & 7) << 4)));
      #pragma unroll
      for (int fm = 0; fm < 2; ++fm){
        int r = wn * 32 + fm * 16 + fr;
        bf16x8 af = *(const bf16x8*)(FT + ((r * 768 + kbf) ^ ((r & 7) << 4)));
        cd[fm] = mfma16(af, bw, cd[fm]);
      }
    }
    __syncthreads();
    if (j == 0) gloadW2(2, W0);   // chunks 4,5 -> W0; drained by j=1's barrier
  }

  // ---- epilogue: tanh -> CL ----
  #pragma unroll
  for (int fm = 0; fm < 2; ++fm){
    int o = wo * 16 + fr;
    float bias = bc[o];
    #pragma unroll
    for (int q = 0; q < 4; ++q){
      int nn = wn * 32 + fm * 16 + ro + q;
      float e = __expf(2.f * (cd[fm][q] + bias));
      *(float*)(CL + ((nn * 256 + 4 * o) ^ ((nn & 7) << 5))) = (e - 1.f) / (e + 1.f);
    }
  }
  __syncthreads();
  {
    int row = tid >> 3, o8 = (tid & 7) * 8;
    int base = (row * 256 + 4 * o8) ^ ((row & 7) << 5);
    f32x4 c0 = *(const f32x4*)(CL + base);
    f32x4 c1 = *(const f32x4*)(CL + base + 16);
    size_t gi = ((size_t)b * NN + n0 + row) * NH + o8;
    f32x4 u0 = *(const f32x4*)&u_l[gi], u1 = *(const f32x4*)&u_l[gi + 4];
    f32x4 h0v = *(const f32x4*)&hNf_l[gi], h1v = *(const f32x4*)&hNf_l[gi + 4];
    f32x4 n0v, n1v;
    #pragma unroll
    for (int q = 0; q < 4; ++q){
      n0v[q] = u0[q] * h0v[q] + (1.f - u0[q]) * c0[q];
      n1v[q] = u1[q] * h1v[q] + (1.f - u1[q]) * c1[q];
    }
    *(f32x4*)&hNf_l[gi] = n0v; *(f32x4*)&hNf_l[gi + 4] = n1v;
    bf16x8 hb;
    #pragma unroll
    for (int q = 0; q < 4; ++q){ hb[q] = (bf16_t)n0v[q]; hb[q + 4] = (bf16_t)n1v[q]; }
    *(bf16x8*)&hN_l[gi] = hb;
    float* cr = cur + (size_t)t * NB * NN * NH + gi;
    *(f32x4*)cr = n0v; *(f32x4*)(cr + 4) = n1v;
    if (t == TSTEPS - 1){
      *(f32x4*)&fin[gi] = n0v; *(f32x4*)&fin[gi + 4] = n1v;
    }
  }
}

// ---------------- host orchestration ----------------------------------------------
extern "C" void kernel_launch(void* const* d_in, const int* in_sizes, int n_in,
                              void* d_out, int out_size, void* d_ws, size_t ws_size,
                              hipStream_t stream){
  const float* inputs = (const float*)d_in[0];
  const float* h0     = (const float*)d_in[1];
  const float* S      = (const float*)d_in[2];
  const float* W_gate = (const float*)d_in[3];
  const float* b_gate = (const float*)d_in[4];
  const float* W_c    = (const float*)d_in[5];
  const float* b_c    = (const float*)d_in[6];
  float* out = (float*)d_out;
  char* ws = (char*)d_ws;

  char*   SP  =          ws + 0;            // 1,048,576
  char*   WgP =          ws + 1048576;      // 196,608
  char*   WcP =          ws + 1245184;      // 98,304
  float*  hNf = (float*) (ws + 1343488);    // 8,388,608 (2 layers)
  bf16_t* hN  = (bf16_t*)(ws + 9732096);    // 4,194,304
  bf16_t* rhN = (bf16_t*)(ws + 13926400);   // 4,194,304
  float*  uN  = (float*) (ws + 18120704);   // 8,388,608
  bf16_t* Dx  = (bf16_t*)(ws + 26509312);   // 8,388,608 -> end 34,897,920
  // S2f (1MB, setup-only) aliases layer-1 Dx region (first written at p=1)
  float*  S2f = (float*) (ws + 26509312 + 4194304);

  k_s2f<<<dim3(1024), 256, 0, stream>>>(S, S2f);
  k_prepS<<<dim3(2048), 256, 0, stream>>>(S, S2f, SP);
  k_prepW<<<dim3(384), 256, 0, stream>>>(W_gate, WgP, 128);
  k_prepW<<<dim3(192), 256, 0, stream>>>(W_c, WcP, 64);
  k_hinit<<<dim3(1024), 256, 0, stream>>>(h0, hNf, hN);

  for (int p = 0; p <= TSTEPS; ++p){
    k_gate<<<dim3(256, 2), 512, 0, stream>>>(inputs, out + (size_t)2 * NB * NN * NH,
                                             p, hN, SP, WgP, b_gate, rhN, uN, Dx);
    k_cand<<<dim3(256, 2), 512, 0, stream>>>(inputs, p, rhN, Dx, SP, WcP, b_c, uN,
                                             hNf, hN, out);
  }
}